// Round 1
// baseline (5721.684 us; speedup 1.0000x reference)
//
#include <hip/hip_runtime.h>
#include <hip/hip_bf16.h>
#include <cstdint>
#include <cstddef>

typedef __bf16 bf16_t;
typedef __bf16 bf16x8 __attribute__((ext_vector_type(8)));
typedef float f32x4 __attribute__((ext_vector_type(4)));
typedef unsigned int u32;
typedef u32 u32x4 __attribute__((ext_vector_type(4)));

#define H_DIM 4096
#define I_DIM 11008

__device__ __forceinline__ u32 pack_bf16(float a, float b) {
    union { __bf16 h[2]; u32 u; } r;
    r.h[0] = (__bf16)a;
    r.h[1] = (__bf16)b;
    return r.u;
}

// XOR-swizzled LDS byte address for a [128 rows][64 k] bf16 tile stored
// row-major (128B per row). f(r) = (r&7)^((r>>2)&7) spreads BOTH the
// staging writes (4 consecutive rows per thread) and the fragment reads
// (16 consecutive rows per 16 lanes) across all 8 16B slots of a row.
__device__ __forceinline__ u32 swz(int r, int kb) {
    return (u32)((r << 7) + kb) ^ (u32)((((r & 7) ^ ((r >> 2) & 7)) << 4));
}

// ---------------- x: f32 -> bf16 ----------------
__global__ void k_cvt_bf16(const float* __restrict__ x, bf16_t* __restrict__ y, int n4) {
    int stride = gridDim.x * blockDim.x;
    for (int i = blockIdx.x * blockDim.x + threadIdx.x; i < n4; i += stride) {
        float4 v = ((const float4*)x)[i];
        uint2 o;
        o.x = pack_bf16(v.x, v.y);
        o.y = pack_bf16(v.z, v.w);
        ((uint2*)y)[i] = o;
    }
}

// ---------------- fused dequant GEMM ----------------
// A: [M, K] bf16 row-major. Q: [K, N] int32 codes 0..15. S: [K/128, N] f32.
// GATEUP: two B matrices, Out = bf16 h = silu(A*Wg) * (A*Wu), [M, N].
// else:   one B matrix,  Out = f32 A*Wd, [M, N].
template <bool GATEUP>
__global__ __launch_bounds__(256) void k_gemm(const bf16_t* __restrict__ A,
                                              const int* __restrict__ Q0,
                                              const float* __restrict__ S0,
                                              const int* __restrict__ Q1,
                                              const float* __restrict__ S1,
                                              void* __restrict__ Out, int K, int N) {
    __shared__ unsigned char lds[GATEUP ? 49152 : 32768];
    unsigned char* ldsA  = lds;
    unsigned char* ldsB0 = lds + 16384;
    unsigned char* ldsB1 = lds + 32768;  // only used when GATEUP

    const int tid  = threadIdx.x;
    const int lane = tid & 63;
    const int wid  = tid >> 6;
    const int wr   = wid >> 1, wc = wid & 1;
    const int m0   = blockIdx.x * 128;
    const int n0   = blockIdx.y * 128;

    f32x4 acc0[4][4];
    f32x4 acc1[4][4];
#pragma unroll
    for (int i = 0; i < 4; ++i)
#pragma unroll
        for (int j = 0; j < 4; ++j) {
            acc0[i][j] = (f32x4)0.f;
            if constexpr (GATEUP) acc1[i][j] = (f32x4)0.f;
        }

    // A staging: thread covers (row = tid>>1, 32 cols at (tid&1)*32)
    const int arow = tid >> 1;
    const int acol = (tid & 1) * 32;
    // B staging: thread covers 4 consecutive n at (tid&31)*4, 8 k at (tid>>5)*8
    const int bn4 = (tid & 31) * 4;
    const int bks = tid >> 5;

    const int frow = lane & 15;          // fragment row/col within 16-block
    const int fkb  = (lane >> 4) * 16;   // fragment k byte offset (8 bf16)

    const int nk = K >> 6;
    for (int kt = 0; kt < nk; ++kt) {
        const int k0  = kt << 6;
        const int grp = k0 >> 7;  // group constant within aligned 64-tile (G=128)

        // ---- stage A (bf16 loads -> swizzled LDS) ----
        {
            const bf16_t* src = A + (size_t)(m0 + arow) * K + (k0 + acol);
            u32x4 v0 = ((const u32x4*)src)[0];
            u32x4 v1 = ((const u32x4*)src)[1];
            u32x4 v2 = ((const u32x4*)src)[2];
            u32x4 v3 = ((const u32x4*)src)[3];
            const int cb = acol * 2;
            *(u32x4*)(ldsA + swz(arow, cb))      = v0;
            *(u32x4*)(ldsA + swz(arow, cb + 16)) = v1;
            *(u32x4*)(ldsA + swz(arow, cb + 32)) = v2;
            *(u32x4*)(ldsA + swz(arow, cb + 48)) = v3;
        }

        // ---- stage B (int codes -> dequant bf16 -> LDS transposed [n][k]) ----
        auto stage_b = [&](const int* __restrict__ Q, const float* __restrict__ S,
                           unsigned char* ldsB) {
            const int* qsrc = Q + (size_t)(k0 + bks * 8) * N + (n0 + bn4);
            float4 sc = *(const float4*)(S + (size_t)grp * N + (n0 + bn4));
            int4 v[8];
#pragma unroll
            for (int j = 0; j < 8; ++j) v[j] = *(const int4*)(qsrc + (size_t)j * N);
            const float s4[4] = {sc.x, sc.y, sc.z, sc.w};
#pragma unroll
            for (int i = 0; i < 4; ++i) {
                const float si = s4[i], oi = -8.f * si;
                u32 w[4];
#pragma unroll
                for (int j = 0; j < 4; ++j) {
                    const int qa = ((const int*)&v[2 * j])[i];
                    const int qb = ((const int*)&v[2 * j + 1])[i];
                    w[j] = pack_bf16(fmaf((float)qa, si, oi), fmaf((float)qb, si, oi));
                }
                u32x4 wv;
                wv.x = w[0]; wv.y = w[1]; wv.z = w[2]; wv.w = w[3];
                *(u32x4*)(ldsB + swz(bn4 + i, bks * 16)) = wv;
            }
        };
        stage_b(Q0, S0, ldsB0);
        if constexpr (GATEUP) stage_b(Q1, S1, ldsB1);

        __syncthreads();

        // ---- compute ----
#pragma unroll
        for (int ks = 0; ks < 2; ++ks) {
            bf16x8 af[4];
#pragma unroll
            for (int f = 0; f < 4; ++f)
                af[f] = *(const bf16x8*)(ldsA + swz(wr * 64 + f * 16 + frow, ks * 64 + fkb));
#pragma unroll
            for (int fn = 0; fn < 4; ++fn) {
                const u32 boff = swz(wc * 64 + fn * 16 + frow, ks * 64 + fkb);
                bf16x8 b0 = *(const bf16x8*)(ldsB0 + boff);
#pragma unroll
                for (int fm = 0; fm < 4; ++fm)
                    acc0[fm][fn] = __builtin_amdgcn_mfma_f32_16x16x32_bf16(af[fm], b0, acc0[fm][fn], 0, 0, 0);
                if constexpr (GATEUP) {
                    bf16x8 b1 = *(const bf16x8*)(ldsB1 + boff);
#pragma unroll
                    for (int fm = 0; fm < 4; ++fm)
                        acc1[fm][fn] = __builtin_amdgcn_mfma_f32_16x16x32_bf16(af[fm], b1, acc1[fm][fn], 0, 0, 0);
                }
            }
        }
        __syncthreads();
    }

    // ---- epilogue ----
    const int col = lane & 15;
    if constexpr (GATEUP) {
        bf16_t* hptr = (bf16_t*)Out;
#pragma unroll
        for (int fm = 0; fm < 4; ++fm) {
#pragma unroll
            for (int r = 0; r < 4; ++r) {
                const size_t row = (size_t)(m0 + wr * 64 + fm * 16 + (lane >> 4) * 4 + r);
#pragma unroll
                for (int fn = 0; fn < 4; ++fn) {
                    const int n = n0 + wc * 64 + fn * 16 + col;
                    float g = acc0[fm][fn][r];
                    float u = acc1[fm][fn][r];
                    float hval = (g / (1.f + __expf(-g))) * u;
                    hptr[row * N + n] = (bf16_t)hval;
                }
            }
        }
    } else {
        float* optr = (float*)Out;
#pragma unroll
        for (int fm = 0; fm < 4; ++fm) {
#pragma unroll
            for (int r = 0; r < 4; ++r) {
                const size_t row = (size_t)(m0 + wr * 64 + fm * 16 + (lane >> 4) * 4 + r);
#pragma unroll
                for (int fn = 0; fn < 4; ++fn) {
                    const int n = n0 + wc * 64 + fn * 16 + col;
                    optr[row * N + n] = acc0[fm][fn][r];
                }
            }
        }
    }
}

extern "C" void kernel_launch(void* const* d_in, const int* in_sizes, int n_in,
                              void* d_out, int out_size, void* d_ws, size_t ws_size,
                              hipStream_t stream) {
    const float* x      = (const float*)d_in[0];
    const int*   gate_q = (const int*)d_in[1];
    const float* gate_s = (const float*)d_in[2];
    const int*   up_q   = (const int*)d_in[3];
    const float* up_s   = (const float*)d_in[4];
    const int*   down_q = (const int*)d_in[5];
    const float* down_s = (const float*)d_in[6];
    float*       out    = (float*)d_out;

    const int  H = H_DIM, I = I_DIM;
    const long M = (long)in_sizes[0] / H;  // 8192

    char*   ws       = (char*)d_ws;
    bf16_t* xb       = (bf16_t*)ws;
    size_t  xb_bytes = (size_t)M * H * sizeof(bf16_t);
    bf16_t* hbuf     = (bf16_t*)(ws + xb_bytes);

    // pick token chunk (multiple of 128) so x_bf16 + h_chunk fit in ws
    long chunk = M;
    while (chunk > 128 && xb_bytes + (size_t)chunk * I * sizeof(bf16_t) > ws_size)
        chunk >>= 1;

    // x -> bf16
    const int n4 = (int)(((size_t)M * H) / 4);
    k_cvt_bf16<<<2048, 256, 0, stream>>>(x, xb, n4);

    for (long c0 = 0; c0 < M; c0 += chunk) {
        const long mc = (M - c0 < chunk) ? (M - c0) : chunk;
        dim3 g1((unsigned)(mc / 128), (unsigned)(I / 128));
        k_gemm<true><<<g1, 256, 0, stream>>>(xb + (size_t)c0 * H, gate_q, gate_s,
                                             up_q, up_s, hbuf, H, I);
        dim3 g2((unsigned)(mc / 128), (unsigned)(H / 128));
        k_gemm<false><<<g2, 256, 0, stream>>>(hbuf, down_q, down_s, nullptr, nullptr,
                                              out + (size_t)c0 * H, I, H);
    }
}

// Round 2
// 4887.392 us; speedup vs baseline: 1.1707x; 1.1707x over previous
//
#include <hip/hip_runtime.h>
#include <hip/hip_bf16.h>
#include <cstdint>
#include <cstddef>

typedef __bf16 bf16_t;
typedef __bf16 bf16x8 __attribute__((ext_vector_type(8)));
typedef float f32x4 __attribute__((ext_vector_type(4)));
typedef unsigned int u32;
typedef u32 u32x4 __attribute__((ext_vector_type(4)));

#define H_DIM 4096
#define I_DIM 11008

__device__ __forceinline__ u32 pack_bf16(float a, float b) {
    union { __bf16 h[2]; u32 u; } r;
    r.h[0] = (__bf16)a;
    r.h[1] = (__bf16)b;
    return r.u;
}

// async global->LDS, 16B per lane. LDS dest is wave-uniform base + lane*16.
__device__ __forceinline__ void gload_lds16(const bf16_t* g, bf16_t* l) {
    __builtin_amdgcn_global_load_lds(
        (const __attribute__((address_space(1))) u32*)g,
        (__attribute__((address_space(3))) u32*)l, 16, 0, 0);
}

// ---------------- x: f32 -> bf16 ----------------
__global__ void k_cvt_bf16(const float* __restrict__ x, bf16_t* __restrict__ y, int n4) {
    int stride = gridDim.x * blockDim.x;
    for (int i = blockIdx.x * blockDim.x + threadIdx.x; i < n4; i += stride) {
        float4 v = ((const float4*)x)[i];
        uint2 o;
        o.x = pack_bf16(v.x, v.y);
        o.y = pack_bf16(v.z, v.w);
        ((uint2*)y)[i] = o;
    }
}

// ---------------- dequant + transpose: Q[K][N] int32 codes -> Wt[N][K] bf16 ----
// 64x64 tile per block, 256 threads.
__global__ __launch_bounds__(256) void k_dequant_t(const int* __restrict__ Q,
                                                   const float* __restrict__ S,
                                                   bf16_t* __restrict__ Wt,
                                                   int K, int N) {
    __shared__ bf16_t tile[64][72];  // +8 pad breaks bank alignment
    const int tid = threadIdx.x;
    const int k0 = blockIdx.x * 64, n0 = blockIdx.y * 64;
    const int grp = k0 >> 7;  // G=128, tile is 64-aligned -> constant
    const int nn = (tid & 15) * 4;
    const int kk = tid >> 4;
    float4 sc = *(const float4*)(S + (size_t)grp * N + n0 + nn);
#pragma unroll
    for (int p = 0; p < 4; ++p) {
        const int k = kk + p * 16;
        int4 q = *(const int4*)(Q + (size_t)(k0 + k) * N + n0 + nn);
        tile[nn + 0][k] = (bf16_t)fmaf((float)q.x, sc.x, -8.f * sc.x);
        tile[nn + 1][k] = (bf16_t)fmaf((float)q.y, sc.y, -8.f * sc.y);
        tile[nn + 2][k] = (bf16_t)fmaf((float)q.z, sc.z, -8.f * sc.z);
        tile[nn + 3][k] = (bf16_t)fmaf((float)q.w, sc.w, -8.f * sc.w);
    }
    __syncthreads();
    const int n = tid >> 2;
    const int kw = (tid & 3) * 16;
    u32x4 v0 = *(u32x4*)&tile[n][kw];
    u32x4 v1 = *(u32x4*)&tile[n][kw + 8];
    bf16_t* dst = Wt + (size_t)(n0 + n) * K + k0 + kw;
    *(u32x4*)dst = v0;
    *((u32x4*)dst + 1) = v1;
}

// ---------------- fast bf16 GEMM (m97 structure) ----------------
// A: [M][K] bf16. B0t/B1t: [N][K] bf16 (pre-dequantized, transposed).
// GATEUP: Out = bf16 silu(A*B0t^T) * (A*B1t^T). else: Out = f32 A*B0t^T.
// 128x128 tile, BK=64, 4 waves (2x2), global_load_lds staging, linear LDS.
template <bool GATEUP>
__global__ __launch_bounds__(256) void k_gemm2(const bf16_t* __restrict__ A,
                                               const bf16_t* __restrict__ B0t,
                                               const bf16_t* __restrict__ B1t,
                                               void* __restrict__ Out, int K, int N) {
    __shared__ unsigned char lds[GATEUP ? 49152 : 32768];
    bf16_t* ldsA  = (bf16_t*)lds;
    bf16_t* ldsB0 = (bf16_t*)(lds + 16384);
    bf16_t* ldsB1 = (bf16_t*)(lds + 32768);

    const int tid  = threadIdx.x;
    const int lane = tid & 63;
    const int wid  = tid >> 6;
    const int wr   = wid >> 1, wc = wid & 1;
    const int m0   = blockIdx.x * 128;
    const int n0   = blockIdx.y * 128;

    f32x4 acc0[4][4];
    f32x4 acc1[4][4];
#pragma unroll
    for (int i = 0; i < 4; ++i)
#pragma unroll
        for (int j = 0; j < 4; ++j) {
            acc0[i][j] = (f32x4)0.f;
            if constexpr (GATEUP) acc1[i][j] = (f32x4)0.f;
        }

    // staging geometry: 128x64 bf16 tile = 16KB = 16 segs of 1KB; wave w takes
    // segs [4w, 4w+4). One gload_lds16 per seg: lane covers row seg*8 + lane/8,
    // 8 k-elems at (lane&7)*8.
    const int srow = lane >> 3;
    const int scol = (lane & 7) << 3;

    const int frow = lane & 15;
    const int fkb  = (lane >> 4) << 4;  // byte offset of 8 k-elems

    const int nk = K >> 6;
    for (int kt = 0; kt < nk; ++kt) {
        const int k0 = kt << 6;
        const bf16_t* As = A   + (size_t)m0 * K + k0;
        const bf16_t* Bs = B0t + (size_t)n0 * K + k0;
        const bf16_t* Cs = GATEUP ? (B1t + (size_t)n0 * K + k0) : nullptr;
#pragma unroll
        for (int j = 0; j < 4; ++j) {
            const int seg = (wid << 2) + j;
            const int row = (seg << 3) + srow;
            gload_lds16(As + (size_t)row * K + scol, ldsA + (seg << 9));
            gload_lds16(Bs + (size_t)row * K + scol, ldsB0 + (seg << 9));
            if constexpr (GATEUP)
                gload_lds16(Cs + (size_t)row * K + scol, ldsB1 + (seg << 9));
        }
        __syncthreads();  // compiler emits vmcnt(0) drain here

#pragma unroll
        for (int ks = 0; ks < 2; ++ks) {
            bf16x8 af[4];
#pragma unroll
            for (int f = 0; f < 4; ++f)
                af[f] = *(const bf16x8*)((unsigned char*)ldsA +
                        ((wr * 64 + f * 16 + frow) << 7) + ks * 64 + fkb);
#pragma unroll
            for (int fn = 0; fn < 4; ++fn) {
                const u32 boff = ((wc * 64 + fn * 16 + frow) << 7) + ks * 64 + fkb;
                bf16x8 b0 = *(const bf16x8*)((unsigned char*)ldsB0 + boff);
#pragma unroll
                for (int fm = 0; fm < 4; ++fm)
                    acc0[fm][fn] = __builtin_amdgcn_mfma_f32_16x16x32_bf16(af[fm], b0, acc0[fm][fn], 0, 0, 0);
                if constexpr (GATEUP) {
                    bf16x8 b1 = *(const bf16x8*)((unsigned char*)ldsB1 + boff);
#pragma unroll
                    for (int fm = 0; fm < 4; ++fm)
                        acc1[fm][fn] = __builtin_amdgcn_mfma_f32_16x16x32_bf16(af[fm], b1, acc1[fm][fn], 0, 0, 0);
                }
            }
        }
        __syncthreads();
    }

    const int col = lane & 15;
    if constexpr (GATEUP) {
        bf16_t* hptr = (bf16_t*)Out;
#pragma unroll
        for (int fm = 0; fm < 4; ++fm) {
#pragma unroll
            for (int r = 0; r < 4; ++r) {
                const size_t row = (size_t)(m0 + wr * 64 + fm * 16 + (lane >> 4) * 4 + r);
#pragma unroll
                for (int fn = 0; fn < 4; ++fn) {
                    const int n = n0 + wc * 64 + fn * 16 + col;
                    float g = acc0[fm][fn][r];
                    float u = acc1[fm][fn][r];
                    hptr[row * N + n] = (bf16_t)((g / (1.f + __expf(-g))) * u);
                }
            }
        }
    } else {
        float* optr = (float*)Out;
#pragma unroll
        for (int fm = 0; fm < 4; ++fm) {
#pragma unroll
            for (int r = 0; r < 4; ++r) {
                const size_t row = (size_t)(m0 + wr * 64 + fm * 16 + (lane >> 4) * 4 + r);
#pragma unroll
                for (int fn = 0; fn < 4; ++fn) {
                    const int n = n0 + wc * 64 + fn * 16 + col;
                    optr[row * N + n] = acc0[fm][fn][r];
                }
            }
        }
    }
}

// ---------------- fallback: fused-dequant GEMM (round-1 kernel) ----------------
__device__ __forceinline__ u32 swz(int r, int kb) {
    return (u32)((r << 7) + kb) ^ (u32)((((r & 7) ^ ((r >> 2) & 7)) << 4));
}

template <bool GATEUP>
__global__ __launch_bounds__(256) void k_gemm(const bf16_t* __restrict__ A,
                                              const int* __restrict__ Q0,
                                              const float* __restrict__ S0,
                                              const int* __restrict__ Q1,
                                              const float* __restrict__ S1,
                                              void* __restrict__ Out, int K, int N) {
    __shared__ unsigned char lds[GATEUP ? 49152 : 32768];
    unsigned char* ldsA  = lds;
    unsigned char* ldsB0 = lds + 16384;
    unsigned char* ldsB1 = lds + 32768;

    const int tid  = threadIdx.x;
    const int lane = tid & 63;
    const int wid  = tid >> 6;
    const int wr   = wid >> 1, wc = wid & 1;
    const int m0   = blockIdx.x * 128;
    const int n0   = blockIdx.y * 128;

    f32x4 acc0[4][4];
    f32x4 acc1[4][4];
#pragma unroll
    for (int i = 0; i < 4; ++i)
#pragma unroll
        for (int j = 0; j < 4; ++j) {
            acc0[i][j] = (f32x4)0.f;
            if constexpr (GATEUP) acc1[i][j] = (f32x4)0.f;
        }

    const int arow = tid >> 1;
    const int acol = (tid & 1) * 32;
    const int bn4 = (tid & 31) * 4;
    const int bks = tid >> 5;
    const int frow = lane & 15;
    const int fkb  = (lane >> 4) * 16;

    const int nk = K >> 6;
    for (int kt = 0; kt < nk; ++kt) {
        const int k0  = kt << 6;
        const int grp = k0 >> 7;
        {
            const bf16_t* src = A + (size_t)(m0 + arow) * K + (k0 + acol);
            u32x4 v0 = ((const u32x4*)src)[0];
            u32x4 v1 = ((const u32x4*)src)[1];
            u32x4 v2 = ((const u32x4*)src)[2];
            u32x4 v3 = ((const u32x4*)src)[3];
            const int cb = acol * 2;
            *(u32x4*)(ldsA + swz(arow, cb))      = v0;
            *(u32x4*)(ldsA + swz(arow, cb + 16)) = v1;
            *(u32x4*)(ldsA + swz(arow, cb + 32)) = v2;
            *(u32x4*)(ldsA + swz(arow, cb + 48)) = v3;
        }
        auto stage_b = [&](const int* __restrict__ Q, const float* __restrict__ S,
                           unsigned char* ldsB) {
            const int* qsrc = Q + (size_t)(k0 + bks * 8) * N + (n0 + bn4);
            float4 sc = *(const float4*)(S + (size_t)grp * N + (n0 + bn4));
            int4 v[8];
#pragma unroll
            for (int j = 0; j < 8; ++j) v[j] = *(const int4*)(qsrc + (size_t)j * N);
            const float s4[4] = {sc.x, sc.y, sc.z, sc.w};
#pragma unroll
            for (int i = 0; i < 4; ++i) {
                const float si = s4[i], oi = -8.f * si;
                u32 w[4];
#pragma unroll
                for (int j = 0; j < 4; ++j) {
                    const int qa = ((const int*)&v[2 * j])[i];
                    const int qb = ((const int*)&v[2 * j + 1])[i];
                    w[j] = pack_bf16(fmaf((float)qa, si, oi), fmaf((float)qb, si, oi));
                }
                u32x4 wv;
                wv.x = w[0]; wv.y = w[1]; wv.z = w[2]; wv.w = w[3];
                *(u32x4*)(ldsB + swz(bn4 + i, bks * 16)) = wv;
            }
        };
        stage_b(Q0, S0, ldsB0);
        if constexpr (GATEUP) stage_b(Q1, S1, ldsB1);
        __syncthreads();
#pragma unroll
        for (int ks = 0; ks < 2; ++ks) {
            bf16x8 af[4];
#pragma unroll
            for (int f = 0; f < 4; ++f)
                af[f] = *(const bf16x8*)(ldsA + swz(wr * 64 + f * 16 + frow, ks * 64 + fkb));
#pragma unroll
            for (int fn = 0; fn < 4; ++fn) {
                const u32 boff = swz(wc * 64 + fn * 16 + frow, ks * 64 + fkb);
                bf16x8 b0 = *(const bf16x8*)(ldsB0 + boff);
#pragma unroll
                for (int fm = 0; fm < 4; ++fm)
                    acc0[fm][fn] = __builtin_amdgcn_mfma_f32_16x16x32_bf16(af[fm], b0, acc0[fm][fn], 0, 0, 0);
                if constexpr (GATEUP) {
                    bf16x8 b1 = *(const bf16x8*)(ldsB1 + boff);
#pragma unroll
                    for (int fm = 0; fm < 4; ++fm)
                        acc1[fm][fn] = __builtin_amdgcn_mfma_f32_16x16x32_bf16(af[fm], b1, acc1[fm][fn], 0, 0, 0);
                }
            }
        }
        __syncthreads();
    }

    const int col = lane & 15;
    if constexpr (GATEUP) {
        bf16_t* hptr = (bf16_t*)Out;
#pragma unroll
        for (int fm = 0; fm < 4; ++fm)
#pragma unroll
            for (int r = 0; r < 4; ++r) {
                const size_t row = (size_t)(m0 + wr * 64 + fm * 16 + (lane >> 4) * 4 + r);
#pragma unroll
                for (int fn = 0; fn < 4; ++fn) {
                    const int n = n0 + wc * 64 + fn * 16 + col;
                    float g = acc0[fm][fn][r];
                    float u = acc1[fm][fn][r];
                    hptr[row * N + n] = (bf16_t)((g / (1.f + __expf(-g))) * u);
                }
            }
    } else {
        float* optr = (float*)Out;
#pragma unroll
        for (int fm = 0; fm < 4; ++fm)
#pragma unroll
            for (int r = 0; r < 4; ++r) {
                const size_t row = (size_t)(m0 + wr * 64 + fm * 16 + (lane >> 4) * 4 + r);
#pragma unroll
                for (int fn = 0; fn < 4; ++fn) {
                    const int n = n0 + wc * 64 + fn * 16 + col;
                    optr[row * N + n] = acc0[fm][fn][r];
                }
            }
    }
}

extern "C" void kernel_launch(void* const* d_in, const int* in_sizes, int n_in,
                              void* d_out, int out_size, void* d_ws, size_t ws_size,
                              hipStream_t stream) {
    const float* x      = (const float*)d_in[0];
    const int*   gate_q = (const int*)d_in[1];
    const float* gate_s = (const float*)d_in[2];
    const int*   up_q   = (const int*)d_in[3];
    const float* up_s   = (const float*)d_in[4];
    const int*   down_q = (const int*)d_in[5];
    const float* down_s = (const float*)d_in[6];
    float*       out    = (float*)d_out;

    const int  H = H_DIM, I = I_DIM;
    const long M = (long)in_sizes[0] / H;  // 8192

    char*        ws       = (char*)d_ws;
    bf16_t*      xb       = (bf16_t*)ws;
    const size_t xb_b     = (size_t)M * H * sizeof(bf16_t);
    const size_t w_b      = (size_t)H * I * sizeof(bf16_t);  // one weight matrix, bf16

    // x -> bf16 (both paths need it)
    const int n4 = (int)(((size_t)M * H) / 4);
    k_cvt_bf16<<<2048, 256, 0, stream>>>(x, xb, n4);

    const size_t fixed = xb_b + 3 * w_b;
    if (ws_size >= fixed + (size_t)128 * I * sizeof(bf16_t)) {
        // ---- fast path: pre-dequantized bf16 weights ----
        bf16_t* wg_t = (bf16_t*)(ws + xb_b);
        bf16_t* wu_t = (bf16_t*)(ws + xb_b + w_b);
        bf16_t* wd_t = (bf16_t*)(ws + xb_b + 2 * w_b);
        bf16_t* hbuf = (bf16_t*)(ws + fixed);

        long chunk = M;
        while (chunk > 128 && fixed + (size_t)chunk * I * sizeof(bf16_t) > ws_size)
            chunk >>= 1;

        dim3 dg1(H / 64, I / 64);
        k_dequant_t<<<dg1, 256, 0, stream>>>(gate_q, gate_s, wg_t, H, I);
        k_dequant_t<<<dg1, 256, 0, stream>>>(up_q, up_s, wu_t, H, I);
        dim3 dg2(I / 64, H / 64);
        k_dequant_t<<<dg2, 256, 0, stream>>>(down_q, down_s, wd_t, I, H);

        for (long c0 = 0; c0 < M; c0 += chunk) {
            const long mc = (M - c0 < chunk) ? (M - c0) : chunk;
            dim3 g1((unsigned)(mc / 128), (unsigned)(I / 128));
            k_gemm2<true><<<g1, 256, 0, stream>>>(xb + (size_t)c0 * H, wg_t, wu_t,
                                                  hbuf, H, I);
            dim3 g2((unsigned)(mc / 128), (unsigned)(H / 128));
            k_gemm2<false><<<g2, 256, 0, stream>>>(hbuf, wd_t, nullptr,
                                                   out + (size_t)c0 * H, I, H);
        }
    } else {
        // ---- fallback: fused-dequant GEMM ----
        bf16_t* hbuf = (bf16_t*)(ws + xb_b);
        long chunk = M;
        while (chunk > 128 && xb_b + (size_t)chunk * I * sizeof(bf16_t) > ws_size)
            chunk >>= 1;
        for (long c0 = 0; c0 < M; c0 += chunk) {
            const long mc = (M - c0 < chunk) ? (M - c0) : chunk;
            dim3 g1((unsigned)(mc / 128), (unsigned)(I / 128));
            k_gemm<true><<<g1, 256, 0, stream>>>(xb + (size_t)c0 * H, gate_q, gate_s,
                                                 up_q, up_s, hbuf, H, I);
            dim3 g2((unsigned)(mc / 128), (unsigned)(H / 128));
            k_gemm<false><<<g2, 256, 0, stream>>>(hbuf, down_q, down_s, nullptr, nullptr,
                                                  out + (size_t)c0 * H, I, H);
        }
    }
}

// Round 5
// 2675.090 us; speedup vs baseline: 2.1389x; 1.8270x over previous
//
#include <hip/hip_runtime.h>
#include <hip/hip_bf16.h>
#include <cstdint>
#include <cstddef>

typedef __bf16 bf16_t;
typedef __bf16 bf16x8 __attribute__((ext_vector_type(8)));
typedef float f32x4 __attribute__((ext_vector_type(4)));
typedef unsigned int u32;
typedef u32 u32x4 __attribute__((ext_vector_type(4)));

#define H_DIM 4096
#define I_DIM 11008

__device__ __forceinline__ u32 pack_bf16(float a, float b) {
    union { __bf16 h[2]; u32 u; } r;
    r.h[0] = (__bf16)a;
    r.h[1] = (__bf16)b;
    return r.u;
}

// async global->LDS: each lane 16B; LDS dest = wave-uniform base + lane*16
__device__ __forceinline__ void gload16(const bf16_t* g, char* l) {
    __builtin_amdgcn_global_load_lds(
        (const __attribute__((address_space(1))) u32*)g,
        (__attribute__((address_space(3))) u32*)l, 16, 0, 0);
}

#define ASM_VMCNT6 asm volatile("s_waitcnt vmcnt(6)" ::: "memory")
#define ASM_VMCNT3 asm volatile("s_waitcnt vmcnt(3)" ::: "memory")
#define ASM_VMCNT0 asm volatile("s_waitcnt vmcnt(0)" ::: "memory")
#define ASM_LGKM0  asm volatile("s_waitcnt lgkmcnt(0)" ::: "memory")
#define ASM_BAR    asm volatile("s_barrier" ::: "memory")

// ============================================================================
// dequant + pack: Q[K][N] int codes, S[K/128][N] -> W packed fragment order.
// Block handles one B-block (32 k x 128 n). Packed unit (cg,lane) holds
// element (n = cg*16 + (lane&15), k = (lane>>4)*8 + e), block stride 4096 elems.
// ============================================================================
__global__ __launch_bounds__(256) void k_dequant_pack(const int* __restrict__ Q,
                                                      const float* __restrict__ S,
                                                      bf16_t* __restrict__ W,
                                                      int K, int N) {
    __shared__ bf16_t tile[128][40];  // [n][k], 80B rows (16B aligned, bank-spread)
    const int tid = threadIdx.x;
    const int k0 = blockIdx.x * 32, n0 = blockIdx.y * 128;
    const int grp = k0 >> 7;
    const int c4 = (tid & 31) * 4;
    const int kr = tid >> 5;
    float4 sc = *(const float4*)(S + (size_t)grp * N + n0 + c4);
#pragma unroll
    for (int p = 0; p < 4; ++p) {
        const int k = kr + p * 8;
        int4 q = *(const int4*)(Q + (size_t)(k0 + k) * N + n0 + c4);
        tile[c4 + 0][k] = (bf16_t)fmaf((float)q.x, sc.x, -8.f * sc.x);
        tile[c4 + 1][k] = (bf16_t)fmaf((float)q.y, sc.y, -8.f * sc.y);
        tile[c4 + 2][k] = (bf16_t)fmaf((float)q.z, sc.z, -8.f * sc.z);
        tile[c4 + 3][k] = (bf16_t)fmaf((float)q.w, sc.w, -8.f * sc.w);
    }
    __syncthreads();
    bf16_t* blk = W + (((size_t)blockIdx.y * (K / 32) + blockIdx.x) << 12);
#pragma unroll
    for (int j = 0; j < 2; ++j) {
        const int u = j * 256 + tid;
        const int cg = u >> 6, ln = u & 63;
        u32x4 v = *(const u32x4*)((const char*)tile +
                                  (size_t)(cg * 16 + (ln & 15)) * 80 + (ln >> 4) * 16);
        *(u32x4*)(blk + (cg << 9) + (ln << 3)) = v;
    }
}

// ============================================================================
// fused gate+up GEMM. A = x (f32, reg-staged + cvt), B0/B1 packed bf16.
// BM=256 BN=128 BK=32, 8 waves (4x2), 4-buf LDS ring, 1 barrier/tile.
// Out: h = silu(x*Wg)*(x*Wu), bf16, packed as down-GEMM A fragments.
// ============================================================================
template <int KDIM>
__global__ __launch_bounds__(512, 2) void k_gateup(const float* __restrict__ x,
                                                   const bf16_t* __restrict__ Wg,
                                                   const bf16_t* __restrict__ Wu,
                                                   bf16_t* __restrict__ hp, int Nb) {
    constexpr int NT = KDIM / 32;
    __shared__ char smem[131072];  // A: 4x16KB @0; B0: 4x8KB @64K; B1: 4x8KB @96K

    const int tid = threadIdx.x, lane = tid & 63, wid = tid >> 6;
    const int wr = wid >> 1, wc = wid & 1;
    const int m0 = blockIdx.x * 256, n0 = blockIdx.y * 128;

    f32x4 accg[4][4], accu[4][4];
#pragma unroll
    for (int i = 0; i < 4; ++i)
#pragma unroll
        for (int j = 0; j < 4; ++j) { accg[i][j] = (f32x4)0.f; accu[i][j] = (f32x4)0.f; }

    // x staging: thread covers row (tid>>1), 16 f32 at (tid&1)*16 within k-tile
    const int arow = tid >> 1, ahalf = tid & 1;
    const float* xsrc = x + (size_t)(m0 + arow) * KDIM + ahalf * 16;
    const u32 wa0 = (u32)(((arow >> 4) << 10) | (((ahalf * 2) * 16 + (arow & 15)) << 4));
    const u32 wa1 = wa0 + 256;

    const bf16_t* wgB = Wg + (((size_t)(n0 >> 7) * NT) << 12);
    const bf16_t* wuB = Wu + (((size_t)(n0 >> 7) * NT) << 12);
    const u32 bsegG = (u32)((wid << 9) + (lane << 3));  // elems (global src)
    const u32 bsegL = (u32)(wid << 10);                 // bytes (LDS dest base)

    f32x4 preA[4], preB[4];

    auto issueB = [&](int kt) {
        char* b0 = smem + 65536 + ((kt & 3) << 13) + bsegL;
        char* b1 = smem + 98304 + ((kt & 3) << 13) + bsegL;
        gload16(wgB + (((size_t)kt) << 12) + bsegG, b0);
        gload16(wuB + (((size_t)kt) << 12) + bsegG, b1);
    };
    auto issueF = [&](int kt, f32x4 (&pre)[4]) {
        const float* s = xsrc + (size_t)kt * 32;
#pragma unroll
        for (int i = 0; i < 4; ++i) pre[i] = *(const f32x4*)(s + i * 4);
    };
    auto dswriteA = [&](int t1, f32x4 (&pre)[4]) {
        u32x4 w0, w1;
        w0.x = pack_bf16(pre[0].x, pre[0].y); w0.y = pack_bf16(pre[0].z, pre[0].w);
        w0.z = pack_bf16(pre[1].x, pre[1].y); w0.w = pack_bf16(pre[1].z, pre[1].w);
        w1.x = pack_bf16(pre[2].x, pre[2].y); w1.y = pack_bf16(pre[2].z, pre[2].w);
        w1.z = pack_bf16(pre[3].x, pre[3].y); w1.w = pack_bf16(pre[3].z, pre[3].w);
        char* ab = smem + ((t1 & 3) << 14);
        *(u32x4*)(ab + wa0) = w0;
        *(u32x4*)(ab + wa1) = w1;
    };

    auto tile_body = [&](int t, f32x4 (&pre)[4]) {
        const char* abuf = smem + ((t & 3) << 14);
        const char* b0buf = smem + 65536 + ((t & 3) << 13);
        const char* b1buf = smem + 98304 + ((t & 3) << 13);
        const u32 fo = (u32)(lane << 4);
        bf16x8 fa[4], f0[4], f1[4];
#pragma unroll
        for (int f = 0; f < 4; ++f) {
            fa[f] = *(const bf16x8*)(abuf + (((wr * 4 + f) << 10) + fo));
            f0[f] = *(const bf16x8*)(b0buf + (((wc * 4 + f) << 10) + fo));
            f1[f] = *(const bf16x8*)(b1buf + (((wc * 4 + f) << 10) + fo));
        }
        if (t <= NT - 3) { ASM_VMCNT6; } else { ASM_VMCNT0; }
        if (t + 1 < NT) dswriteA(t + 1, pre);
        if (t + 3 < NT) { issueB(t + 3); issueF(t + 3, pre); }
        ASM_LGKM0;
        __builtin_amdgcn_s_setprio(1);
#pragma unroll
        for (int fn = 0; fn < 4; ++fn)
#pragma unroll
            for (int fm = 0; fm < 4; ++fm) {
                accg[fm][fn] = __builtin_amdgcn_mfma_f32_16x16x32_bf16(fa[fm], f0[fn], accg[fm][fn], 0, 0, 0);
                accu[fm][fn] = __builtin_amdgcn_mfma_f32_16x16x32_bf16(fa[fm], f1[fn], accu[fm][fn], 0, 0, 0);
            }
        __builtin_amdgcn_s_setprio(0);
        ASM_BAR;
    };

    // prologue: batches 0,1 in flight; A(0) written; batch 2 issued
    issueB(0); issueF(0, preA);
    issueB(1); issueF(1, preB);
    ASM_VMCNT6;               // batch0 landed
    dswriteA(0, preA);
    issueB(2); issueF(2, preA);
    ASM_LGKM0;
    ASM_BAR;

    for (int t = 0; t < NT; t += 2) {
        tile_body(t, preB);       // consumes f(t+1) (odd set), refills with f(t+3)
        tile_body(t + 1, preA);   // consumes f(t+2) (even set), refills with f(t+4)
    }

    // ---- epilogue: silu(g)*u -> bf16, bounce via LDS, write packed h ----
    bf16_t* bounce = (bf16_t*)smem;  // [256][136] bf16 = 69632B
    const int ehr = lane >> 4, col16 = lane & 15;
#pragma unroll
    for (int fm = 0; fm < 4; ++fm)
#pragma unroll
        for (int fn = 0; fn < 4; ++fn)
#pragma unroll
            for (int r = 0; r < 4; ++r) {
                float g = accg[fm][fn][r];
                float u = accu[fm][fn][r];
                float h = (g / (1.f + __expf(-g))) * u;
                const int row_l = wr * 64 + fm * 16 + ehr * 4 + r;
                const int col_l = wc * 64 + fn * 16 + col16;
                bounce[row_l * 136 + col_l] = (bf16_t)h;
            }
    ASM_LGKM0;
    ASM_BAR;
    const size_t hblk = (size_t)blockIdx.x * (Nb / 32) + (n0 >> 5);
#pragma unroll
    for (int j = 0; j < 8; ++j) {
        const int u = j * 512 + tid;
        const int ktl = u >> 10, rg = (u >> 6) & 15, ln = u & 63;
        u32x4 v = *(const u32x4*)((const char*)bounce +
                                  (size_t)(rg * 16 + (ln & 15)) * 272 + ktl * 64 + (ln >> 4) * 16);
        *(u32x4*)(hp + ((hblk + ktl) << 13) + (rg << 9) + (ln << 3)) = v;
    }
}

// ============================================================================
// down GEMM. A = h packed bf16 (gload), B = Wd packed bf16 (gload).
// BM=256 BN=128 BK=32, 8 waves, 4-buf ring, 1 barrier/tile. Out f32 row-major.
// ============================================================================
template <int KDIM>
__global__ __launch_bounds__(512, 2) void k_down(const bf16_t* __restrict__ hp,
                                                 const bf16_t* __restrict__ Wd,
                                                 float* __restrict__ out, int Nb) {
    constexpr int NT = KDIM / 32;
    __shared__ char smem[98304];  // A: 4x16KB @0; B: 4x8KB @64K

    const int tid = threadIdx.x, lane = tid & 63, wid = tid >> 6;
    const int wr = wid >> 1, wc = wid & 1;
    const int m0 = blockIdx.x * 256, n0 = blockIdx.y * 128;

    f32x4 acc[4][4];
#pragma unroll
    for (int i = 0; i < 4; ++i)
#pragma unroll
        for (int j = 0; j < 4; ++j) acc[i][j] = (f32x4)0.f;

    const bf16_t* hpB = hp + (((size_t)blockIdx.x * NT) << 13);
    const bf16_t* wdB = Wd + (((size_t)(n0 >> 7) * NT) << 12);
    const u32 lseg = (u32)(lane << 3);

    auto issue = [&](int kt) {
        char* ab = smem + ((kt & 3) << 14);
        char* bb = smem + 65536 + ((kt & 3) << 13);
        const bf16_t* as = hpB + (((size_t)kt) << 13);
        const bf16_t* bs = wdB + (((size_t)kt) << 12);
        gload16(as + ((wid * 2 + 0) << 9) + lseg, ab + ((wid * 2 + 0) << 10));
        gload16(as + ((wid * 2 + 1) << 9) + lseg, ab + ((wid * 2 + 1) << 10));
        gload16(bs + (wid << 9) + lseg, bb + (wid << 10));
    };

    issue(0); issue(1); issue(2);
    ASM_VMCNT6;  // batch0 landed
    ASM_BAR;

    for (int t = 0; t < NT; ++t) {
        const char* abuf = smem + ((t & 3) << 14);
        const char* bbuf = smem + 65536 + ((t & 3) << 13);
        const u32 fo = (u32)(lane << 4);
        bf16x8 fa[4], fb[4];
#pragma unroll
        for (int f = 0; f < 4; ++f) {
            fa[f] = *(const bf16x8*)(abuf + (((wr * 4 + f) << 10) + fo));
            fb[f] = *(const bf16x8*)(bbuf + (((wc * 4 + f) << 10) + fo));
        }
        if (t <= NT - 3) { ASM_VMCNT3; } else { ASM_VMCNT0; }
        if (t + 3 < NT) issue(t + 3);
        ASM_LGKM0;
        __builtin_amdgcn_s_setprio(1);
#pragma unroll
        for (int fn = 0; fn < 4; ++fn)
#pragma unroll
            for (int fm = 0; fm < 4; ++fm)
                acc[fm][fn] = __builtin_amdgcn_mfma_f32_16x16x32_bf16(fa[fm], fb[fn], acc[fm][fn], 0, 0, 0);
        __builtin_amdgcn_s_setprio(0);
        ASM_BAR;
    }

    const int ehr = lane >> 4, col16 = lane & 15;
#pragma unroll
    for (int fm = 0; fm < 4; ++fm)
#pragma unroll
        for (int fn = 0; fn < 4; ++fn) {
            const int col = n0 + wc * 64 + fn * 16 + col16;
#pragma unroll
            for (int r = 0; r < 4; ++r) {
                const int row = m0 + wr * 64 + fm * 16 + ehr * 4 + r;
                out[(size_t)row * Nb + col] = acc[fm][fn][r];
            }
        }
}

// ============================================================================
extern "C" void kernel_launch(void* const* d_in, const int* in_sizes, int n_in,
                              void* d_out, int out_size, void* d_ws, size_t ws_size,
                              hipStream_t stream) {
    const float* x      = (const float*)d_in[0];
    const int*   gate_q = (const int*)d_in[1];
    const float* gate_s = (const float*)d_in[2];
    const int*   up_q   = (const int*)d_in[3];
    const float* up_s   = (const float*)d_in[4];
    const int*   down_q = (const int*)d_in[5];
    const float* down_s = (const float*)d_in[6];
    float*       out    = (float*)d_out;

    const int  H = H_DIM, I = I_DIM;
    const long M = (long)in_sizes[0] / H;  // 8192

    char*        ws = (char*)d_ws;
    const size_t wb = (size_t)H * I * sizeof(bf16_t);  // 90.2 MB per weight
    bf16_t* wg = (bf16_t*)ws;
    bf16_t* wu = (bf16_t*)(ws + wb);
    bf16_t* wd = (bf16_t*)(ws + 2 * wb);
    bf16_t* hp = (bf16_t*)(ws + 3 * wb);

    // token chunk sized to remaining workspace (ws >= 517MB proven in round 2)
    long avail = (long)ws_size - (long)(3 * wb);
    long C = avail > 0 ? avail / ((long)I * (long)sizeof(bf16_t)) : 256;
    C = (C / 256) * 256;
    if (C > M) C = M;
    if (C < 256) C = 256;

    dim3 dq1(H / 32, I / 128);
    k_dequant_pack<<<dq1, 256, 0, stream>>>(gate_q, gate_s, wg, H, I);
    k_dequant_pack<<<dq1, 256, 0, stream>>>(up_q, up_s, wu, H, I);
    dim3 dq2(I / 32, H / 128);
    k_dequant_pack<<<dq2, 256, 0, stream>>>(down_q, down_s, wd, I, H);

    for (long c0 = 0; c0 < M; c0 += C) {
        const long mc = (M - c0 < C) ? (M - c0) : C;
        dim3 g1((unsigned)(mc / 256), (unsigned)(I / 128));
        k_gateup<H_DIM><<<g1, 512, 0, stream>>>(x + (size_t)c0 * H, wg, wu, hp, I);
        dim3 g2((unsigned)(mc / 256), (unsigned)(H / 128));
        k_down<I_DIM><<<g2, 512, 0, stream>>>(hp, wd, out + (size_t)c0 * H, H);
    }
}